// Round 2
// baseline (175.881 us; speedup 1.0000x reference)
//
#include <hip/hip_runtime.h>
#include <hip/hip_bf16.h>

#define B_DIM 8192
#define D_DIM 256
#define GRID_GEMM 1024

constexpr float INV_T = 14.285714285714286f;   // 1/0.07; also the logsumexp shift M

typedef __bf16 bf16x8 __attribute__((ext_vector_type(8)));
typedef float  f32x4  __attribute__((ext_vector_type(4)));

#define GLOBAL_U32(p) ((const __attribute__((address_space(1))) unsigned int*)(p))
#define LDS_U32(p)    ((__attribute__((address_space(3))) unsigned int*)(p))

__device__ inline unsigned short f2bf(float f) {
    union { float f; unsigned u; } x; x.f = f;
    unsigned r = x.u + 0x7fffu + ((x.u >> 16) & 1u);  // RNE
    return (unsigned short)(r >> 16);
}

// Kernel 1: q = normalize(h+r), t = normalize(t) -> bf16 workspace.
// Block 0 additionally zeroes rowsum/diagsum/ticket (replaces hipMemsetAsync).
__global__ __launch_bounds__(256) void norm_kernel(
    const float* __restrict__ h, const float* __restrict__ r,
    const float* __restrict__ t,
    unsigned short* __restrict__ qws, unsigned short* __restrict__ tws,
    float* __restrict__ rowsum, float* __restrict__ diagsum, int* __restrict__ ticket)
{
    if (blockIdx.x == 0) {
        float4* rs4 = (float4*)rowsum;
#pragma unroll
        for (int i = 0; i < 8; ++i)
            rs4[threadIdx.x * 8 + i] = make_float4(0.f, 0.f, 0.f, 0.f);
        if (threadIdx.x == 0) { *diagsum = 0.f; *ticket = 0; }
    }

    int wave = threadIdx.x >> 6;
    int lane = threadIdx.x & 63;
    int task = blockIdx.x * 4 + wave;
    bool isQ = task < B_DIM;
    int row  = isQ ? task : task - B_DIM;

    float4 v;
    if (isQ) {
        float4 a = ((const float4*)h)[row * 64 + lane];
        float4 b = ((const float4*)r)[row * 64 + lane];
        v = make_float4(a.x + b.x, a.y + b.y, a.z + b.z, a.w + b.w);
    } else {
        v = ((const float4*)t)[row * 64 + lane];
    }
    float s = v.x * v.x + v.y * v.y + v.z * v.z + v.w * v.w;
#pragma unroll
    for (int off = 32; off; off >>= 1) s += __shfl_xor(s, off, 64);
    float scale = 1.0f / fmaxf(sqrtf(s), 1e-12f);

    ushort4 o;
    o.x = f2bf(v.x * scale);
    o.y = f2bf(v.y * scale);
    o.z = f2bf(v.z * scale);
    o.w = f2bf(v.w * scale);
    ushort4* dst = (ushort4*)(isQ ? qws : tws);
    dst[row * 64 + lane] = o;
}

// Kernel 2: fused GEMM + exp-sum + diagonal + (last block) finalize.
// Grid 1024 = 64 row-blocks x 16 col-chunks. Block: 128 rows x 512 cols.
// Wave: 32 rows (A in registers, 64 VGPRs) x 64-col nt-tiles (8 iters).
// B staged global->LDS via global_load_lds(16B), XOR-swizzled chunk layout
// (p = c ^ (n&7)) so frag ds_read_b128s are conflict-free without padding.
__global__ __launch_bounds__(256, 4) void gemm_lse_kernel(
    const unsigned char* __restrict__ qws, const unsigned char* __restrict__ tws,
    float* __restrict__ rowsum, float* __restrict__ diagsum,
    int* __restrict__ ticket, float* __restrict__ out)
{
    __shared__ __align__(16) unsigned char bTile[64 * 512];
    __shared__ float wred[4];
    __shared__ int lastflag;

    const int tid  = threadIdx.x;
    const int lane = tid & 63;
    const int w    = tid >> 6;
    const int quad = lane >> 4;
    const int l15  = lane & 15;

    const int rb   = blockIdx.x & 63;
    const int nc   = blockIdx.x >> 6;
    const int row0 = rb * 128;
    const int rw0  = row0 + w * 32;       // this wave's 32 rows
    const int col0 = nc * 512;

    // ---- A fragments in registers: rows rw0..rw0+31, full K=256 ----
    // 16x16x32 A layout: m = l15, k = ks*32 + quad*8 + j  -> 16B contiguous
    bf16x8 a[2][8];
#pragma unroll
    for (int rt = 0; rt < 2; ++rt) {
        const unsigned char* base =
            qws + (size_t)(rw0 + rt * 16 + l15) * 512 + quad * 16;
#pragma unroll
        for (int ks = 0; ks < 8; ++ks)
            a[rt][ks] = *(const bf16x8*)(base + ks * 64);
    }

    // ---- staging address precompute: slot s -> (row n, phys chunk p) ----
    // logical chunk c = p ^ (n&7); global offset = n*512 + c*16
    int rel[8];
#pragma unroll
    for (int it = 0; it < 8; ++it) {
        int s = it * 256 + tid;
        int n = s >> 5;
        int c = (s & 31) ^ (n & 7);
        rel[it] = n * 512 + c * 16;
    }
    unsigned char* ldsdst = bTile + tid * 16;

    float rowacc[2][4] = {{0.f,0.f,0.f,0.f},{0.f,0.f,0.f,0.f}};
    float diagacc = 0.f;

    for (int nt = 0; nt < 8; ++nt) {
        const int n0 = col0 + nt * 64;
        const unsigned char* gsrc = tws + (size_t)n0 * 512;

        __syncthreads();   // previous tile's reads done
#pragma unroll
        for (int it = 0; it < 8; ++it)
            __builtin_amdgcn_global_load_lds(GLOBAL_U32(gsrc + rel[it]),
                                             LDS_U32(ldsdst + it * 4096),
                                             16, 0, 0);
        __syncthreads();   // staging complete (vmcnt drained by barrier)

        f32x4 acc[2][4];
#pragma unroll
        for (int rt = 0; rt < 2; ++rt)
#pragma unroll
            for (int ct = 0; ct < 4; ++ct)
                acc[rt][ct] = f32x4{0.f, 0.f, 0.f, 0.f};

#pragma unroll
        for (int ks = 0; ks < 8; ++ks) {
#pragma unroll
            for (int ct = 0; ct < 4; ++ct) {
                int n = ct * 16 + l15;
                int p = (ks * 4 + quad) ^ (n & 7);
                bf16x8 b = *(const bf16x8*)(bTile + n * 512 + p * 16);
                acc[0][ct] = __builtin_amdgcn_mfma_f32_16x16x32_bf16(
                    a[0][ks], b, acc[0][ct], 0, 0, 0);
                acc[1][ct] = __builtin_amdgcn_mfma_f32_16x16x32_bf16(
                    a[1][ks], b, acc[1][ct], 0, 0, 0);
            }
        }

        // epilogue: accumulate exp(sim - M) per-lane (no cross-lane work here)
#pragma unroll
        for (int rt = 0; rt < 2; ++rt) {
#pragma unroll
            for (int ct = 0; ct < 4; ++ct) {
                const bool isdiag = (n0 + ct * 16) == (rw0 + rt * 16); // wave-uniform
#pragma unroll
                for (int i = 0; i < 4; ++i) {
                    float d = acc[rt][ct][i];
                    rowacc[rt][i] += __expf(fmaf(d, INV_T, -INV_T));
                    if (isdiag && l15 == quad * 4 + i)
                        diagacc += d * INV_T;
                }
            }
        }
    }

    // ---- once per block: reduce row partials across the 16 l15 lanes ----
#pragma unroll
    for (int rt = 0; rt < 2; ++rt)
#pragma unroll
        for (int i = 0; i < 4; ++i) {
            float s = rowacc[rt][i];
            s += __shfl_xor(s, 1, 64);
            s += __shfl_xor(s, 2, 64);
            s += __shfl_xor(s, 4, 64);
            s += __shfl_xor(s, 8, 64);
            if (l15 == 0)
                atomicAdd(&rowsum[rw0 + rt * 16 + quad * 4 + i], s);
        }

    float dsum = diagacc;
#pragma unroll
    for (int off = 32; off; off >>= 1) dsum += __shfl_xor(dsum, off, 64);
    if (lane == 0 && dsum != 0.f) atomicAdd(diagsum, dsum);

    // ---- ticket: last block computes the loss ----
    __syncthreads();   // all this block's atomics issued & completed (vmcnt drain)
    if (tid == 0) {
        __threadfence();
        int old = __hip_atomic_fetch_add(ticket, 1, __ATOMIC_ACQ_REL,
                                         __HIP_MEMORY_SCOPE_AGENT);
        lastflag = (old == GRID_GEMM - 1);
    }
    __syncthreads();
    if (!lastflag) return;

    float lsum = 0.f;
    for (int rr = tid; rr < B_DIM; rr += 256) {
        float rs = __hip_atomic_load(&rowsum[rr], __ATOMIC_RELAXED,
                                     __HIP_MEMORY_SCOPE_AGENT);
        lsum += __logf(rs);
    }
#pragma unroll
    for (int off = 32; off; off >>= 1) lsum += __shfl_xor(lsum, off, 64);
    if (lane == 0) wred[w] = lsum;
    __syncthreads();
    if (tid == 0) {
        float ds = __hip_atomic_load(diagsum, __ATOMIC_RELAXED,
                                     __HIP_MEMORY_SCOPE_AGENT);
        float total = wred[0] + wred[1] + wred[2] + wred[3]
                    + (float)B_DIM * INV_T   // + M per row
                    - ds;                    // - sum of positive logits
        out[0] = total / (float)B_DIM;
    }
}

extern "C" void kernel_launch(void* const* d_in, const int* in_sizes, int n_in,
                              void* d_out, int out_size, void* d_ws, size_t ws_size,
                              hipStream_t stream)
{
    const float* h = (const float*)d_in[0];
    const float* r = (const float*)d_in[1];
    const float* t = (const float*)d_in[2];

    unsigned char* ws = (unsigned char*)d_ws;
    unsigned short* qws = (unsigned short*)ws;                        // 4 MB
    unsigned short* tws = (unsigned short*)(ws + 4u * 1024 * 1024);   // 4 MB
    float* rowsum  = (float*)(ws + 8u * 1024 * 1024);                 // 32 KB
    float* diagsum = (float*)(ws + 8u * 1024 * 1024 + 32u * 1024);
    int*   ticket  = (int*)  (ws + 8u * 1024 * 1024 + 32u * 1024 + 16);

    norm_kernel<<<4096, 256, 0, stream>>>(h, r, t, qws, tws, rowsum, diagsum, ticket);
    gemm_lse_kernel<<<GRID_GEMM, 256, 0, stream>>>(
        (const unsigned char*)qws, (const unsigned char*)tws,
        rowsum, diagsum, ticket, (float*)d_out);
}